// Round 6
// baseline (969.248 us; speedup 1.0000x reference)
//
#include <hip/hip_runtime.h>

// NeuralConvNetwork (Duvenaud fingerprint GNN), MI355X.
// Round 6: occupancy attack. R5: layer2 406us, occupancy stuck at 23% (~2
// waves/SIMD: 120 VGPR + 96 AGPR = 216 -> 256-reg slot). MFMA busy is only
// ~59us; ~85% of time is unhidden gather latency. Changes:
//   - 512-thread blocks (8 waves): layer2 JMAX 8->4 (48 AGPR), layers 0/1 one
//     N-tile per wave (12 AGPR). __launch_bounds__(512,4) caps waves at <=128
//     total regs -> 4 waves/SIMD.
//   - gather: 16 row-groups x 32 chunk-lanes, 3 batched row-passes; bond rows
//     on the idle ch>=25 lanes (balanced across all waves).
//   - everything else (H layout, weight packing, fused norm/relu/molsum) as R5.

#define XS 100   // bf16 elems per intermediate activation row (exact)

typedef __attribute__((ext_vector_type(8))) short short8;
typedef __attribute__((ext_vector_type(4))) float float4v;

__device__ __forceinline__ float bf2f(unsigned u) { return __uint_as_float(u << 16); }
__device__ __forceinline__ unsigned short f2bf(float f) {
    unsigned b = __float_as_uint(f);
    return (unsigned short)((b + 0x7FFFu + ((b >> 16) & 1u)) >> 16);  // RNE
}
__device__ __forceinline__ unsigned pack2(float a, float b) {
    return (unsigned)f2bf(a) | ((unsigned)f2bf(b) << 16);
}

// ---- weight prep: Wt[dg][n][k]; k<F_IN -> Ws[k][n], SELF_PAD<=k<SELF_PAD+F_IN
//      -> Wd[dg][k-SELF_PAD][n], 2*SELF_PAD<=k<2*SELF_PAD+6 -> Wd bond rows.
__global__ void prep_weights(const float* __restrict__ Ws, const float* __restrict__ bs,
                             const float* __restrict__ Wd, const float* __restrict__ bd,
                             int F_IN, int F_OUT, int F_OUT_PAD, int KP, int SELF_PAD,
                             unsigned short* __restrict__ Wt, float* __restrict__ bc)
{
    int id = blockIdx.x * 256 + threadIdx.x;
    int total = 4 * F_OUT_PAD * KP;
    if (id >= total) return;
    int k  = id % KP;
    int nq = (id / KP) % F_OUT_PAD;
    int dg = id / (KP * F_OUT_PAD);
    float v = 0.f;
    if (nq < F_OUT) {
        if (k < F_IN)                                   v = Ws[(size_t)k * F_OUT + nq];
        else if (k >= SELF_PAD && k < SELF_PAD + F_IN)  v = Wd[((size_t)dg * (F_IN + 6) + (k - SELF_PAD)) * F_OUT + nq];
        else if (k >= 2 * SELF_PAD && k < 2 * SELF_PAD + 6)
            v = Wd[((size_t)dg * (F_IN + 6) + F_IN + (k - 2 * SELF_PAD)) * F_OUT + nq];
    }
    Wt[id] = f2bf(v);
    if (k == 0)
        bc[dg * F_OUT_PAD + nq] = (nq < F_OUT) ? (bs[nq] + bd[(size_t)dg * F_OUT + nq]) : 0.f;
}

// ---- gather, bf16 input rows of XS=100. H: self@[0,100), nbr@[104,204),
//      bond@[208,214), zeros elsewhere up to KP=224.  512 threads.
template<int DEG, int SP>
__device__ __forceinline__ void gather_bf16(
    unsigned short* Hs, const unsigned short* __restrict__ x,
    const float* __restrict__ bondf,
    const int* __restrict__ an, const int* __restrict__ bn,
    int seg, int B40)
{
    const int tid = threadIdx.x;                    // 0..511
    const int ch  = tid & 31;
    const int rg  = tid >> 5;                       // 0..15

    if (ch < 25) {                                  // atom rows: 25 x uint2 = 100 elems
        int ai[3][DEG];
        #pragma unroll
        for (int p = 0; p < 3; ++p) {
            const int r = rg + 16 * p;
            if (r < 40) {
                const int ri = B40 + r;
                #pragma unroll
                for (int d = 0; d < DEG; ++d) ai[p][d] = an[(size_t)ri * DEG + d];
            }
        }
        uint2 sv[3], nv[3][DEG];
        #pragma unroll
        for (int p = 0; p < 3; ++p) {
            const int r = rg + 16 * p;
            if (r < 40) {
                sv[p] = *(const uint2*)(x + (size_t)(seg + B40 + r) * XS + ch * 4);
                #pragma unroll
                for (int d = 0; d < DEG; ++d)
                    nv[p][d] = *(const uint2*)(x + (size_t)ai[p][d] * XS + ch * 4);
            }
        }
        #pragma unroll
        for (int p = 0; p < 3; ++p) {
            const int r = rg + 16 * p;
            if (r < 40) {
                unsigned short* hrow = Hs + r * SP;
                *(uint2*)(hrow + ch * 4) = sv[p];   // self: bit copy
                float s0 = 0.f, s1 = 0.f, s2 = 0.f, s3 = 0.f;
                #pragma unroll
                for (int d = 0; d < DEG; ++d) {
                    s0 += bf2f(nv[p][d].x & 0xFFFFu); s1 += bf2f(nv[p][d].x >> 16);
                    s2 += bf2f(nv[p][d].y & 0xFFFFu); s3 += bf2f(nv[p][d].y >> 16);
                }
                uint2 o; o.x = pack2(s0, s1); o.y = pack2(s2, s3);
                *(uint2*)(hrow + 104 + ch * 4) = o;
            }
        }
    } else {                                        // bond rows on ch 25..31 lanes
        const int idx = rg * 7 + (ch - 25);         // 0..111
        if (idx < 40) {
            const int ri = B40 + idx;
            int bi[DEG];
            #pragma unroll
            for (int d = 0; d < DEG; ++d) bi[d] = bn[(size_t)ri * DEG + d];
            float2 v0[DEG], v1[DEG], v2[DEG];
            #pragma unroll
            for (int d = 0; d < DEG; ++d) {
                const float* bp = bondf + (size_t)bi[d] * 6;
                v0[d] = *(const float2*)bp;
                v1[d] = *(const float2*)(bp + 2);
                v2[d] = *(const float2*)(bp + 4);
            }
            float s0 = 0.f, s1 = 0.f, s2 = 0.f, s3 = 0.f, s4 = 0.f, s5 = 0.f;
            #pragma unroll
            for (int d = 0; d < DEG; ++d) {
                s0 += v0[d].x; s1 += v0[d].y; s2 += v1[d].x;
                s3 += v1[d].y; s4 += v2[d].x; s5 += v2[d].y;
            }
            unsigned short* hrow = Hs + idx * SP;
            uint4 w; w.x = pack2(s0, s1); w.y = pack2(s2, s3); w.z = pack2(s4, s5); w.w = 0;
            *(uint4*)(hrow + 208) = w;              // cols 208-215 (214-215 zero)
            *(uint4*)(hrow + 216) = make_uint4(0, 0, 0, 0);
        }
    }
    // zero pads: self [100,104) + nbr [204,208) rows 0..39; pad rows 40..47 full
    for (int i = tid; i < 80; i += 512) {
        unsigned short* p = Hs + (i >> 1) * SP + ((i & 1) ? 204 : 100);
        *(uint2*)p = make_uint2(0, 0);
    }
    for (int i = tid; i < 8 * 28; i += 512)
        *(uint4*)(Hs + (40 + i / 28) * SP + (i % 28) * 8) = make_uint4(0, 0, 0, 0);
}

// ---- gather, fp32 input rows of 62. H: self@[0,62), nbr@[64,126),
//      bond@[128,134), zeros elsewhere up to KP=160.  512 threads.
template<int DEG, int SP>
__device__ __forceinline__ void gather_f32(
    unsigned short* Hs, const float* __restrict__ x,
    const float* __restrict__ bondf,
    const int* __restrict__ an, const int* __restrict__ bn,
    int seg, int B40)
{
    const int tid = threadIdx.x;
    const int ch  = tid & 31;
    const int rg  = tid >> 5;

    if (ch < 31) {                                  // 31 x float2 = 62 elems/row
        int ai[3][DEG];
        #pragma unroll
        for (int p = 0; p < 3; ++p) {
            const int r = rg + 16 * p;
            if (r < 40) {
                const int ri = B40 + r;
                #pragma unroll
                for (int d = 0; d < DEG; ++d) ai[p][d] = an[(size_t)ri * DEG + d];
            }
        }
        float2 sv[3], nv[3][DEG];
        #pragma unroll
        for (int p = 0; p < 3; ++p) {
            const int r = rg + 16 * p;
            if (r < 40) {
                sv[p] = *(const float2*)(x + (size_t)(seg + B40 + r) * 62 + ch * 2);
                #pragma unroll
                for (int d = 0; d < DEG; ++d)
                    nv[p][d] = *(const float2*)(x + (size_t)ai[p][d] * 62 + ch * 2);
            }
        }
        #pragma unroll
        for (int p = 0; p < 3; ++p) {
            const int r = rg + 16 * p;
            if (r < 40) {
                unsigned short* hrow = Hs + r * SP;
                *(unsigned*)(hrow + ch * 2) = pack2(sv[p].x, sv[p].y);
                float s0 = 0.f, s1 = 0.f;
                #pragma unroll
                for (int d = 0; d < DEG; ++d) { s0 += nv[p][d].x; s1 += nv[p][d].y; }
                *(unsigned*)(hrow + 64 + ch * 2) = pack2(s0, s1);
            }
        }
    }
    if (tid < 40) {                                 // bond rows
        const int ri = B40 + tid;
        int bi[DEG];
        #pragma unroll
        for (int d = 0; d < DEG; ++d) bi[d] = bn[(size_t)ri * DEG + d];
        float2 v0[DEG], v1[DEG], v2[DEG];
        #pragma unroll
        for (int d = 0; d < DEG; ++d) {
            const float* bp = bondf + (size_t)bi[d] * 6;
            v0[d] = *(const float2*)bp;
            v1[d] = *(const float2*)(bp + 2);
            v2[d] = *(const float2*)(bp + 4);
        }
        float s0 = 0.f, s1 = 0.f, s2 = 0.f, s3 = 0.f, s4 = 0.f, s5 = 0.f;
        #pragma unroll
        for (int d = 0; d < DEG; ++d) {
            s0 += v0[d].x; s1 += v0[d].y; s2 += v1[d].x;
            s3 += v1[d].y; s4 += v2[d].x; s5 += v2[d].y;
        }
        unsigned short* hrow = Hs + tid * SP;
        uint4 w; w.x = pack2(s0, s1); w.y = pack2(s2, s3); w.z = pack2(s4, s5); w.w = 0;
        *(uint4*)(hrow + 128) = w;                  // cols 128-135
        *(uint4*)(hrow + 136) = make_uint4(0, 0, 0, 0);
        *(uint4*)(hrow + 144) = make_uint4(0, 0, 0, 0);
        *(uint4*)(hrow + 152) = make_uint4(0, 0, 0, 0);
    }
    for (int i = tid; i < 80; i += 512)             // self pad [62,64), nbr pad [126,128)
        *(unsigned*)(Hs + (i >> 1) * SP + ((i & 1) ? 126 : 62)) = 0;
    for (int i = tid; i < 8 * 20; i += 512)         // pad rows 40..47, 160 cols
        *(uint4*)(Hs + (40 + i / 20) * SP + (i % 20) * 8) = make_uint4(0, 0, 0, 0);
}

template<int F_IN, int F_OUT, int F_OUT_PAD, int SELF_PAD, bool LAST, bool BF16IN>
__global__ __launch_bounds__(512, 4) void layer_mfma(
    const void* __restrict__ xin,
    const float* __restrict__ bondf,
    const int* __restrict__ an1, const int* __restrict__ bn1,
    const int* __restrict__ an2, const int* __restrict__ bn2,
    const int* __restrict__ an3, const int* __restrict__ bn3,
    const int* __restrict__ an4, const int* __restrict__ bn4,
    const unsigned short* __restrict__ Wt,  // [4][F_OUT_PAD][KP] bf16
    const float* __restrict__ bcomb,        // [4][F_OUT_PAD] fp32
    unsigned short* __restrict__ xout,      // layers 0/1: [500000, XS] bf16
    float* __restrict__ molout)             // layer 2:    [25000, 512] fp32
{
    constexpr int KP   = (2 * SELF_PAD + 6 + 31) & ~31;   // 160 / 224
    constexpr int SP   = KP + 8;
    constexpr int NT   = F_OUT_PAD / 16;                  // 7 / 32
    constexpr int JMAX = (NT + 7) / 8;                    // 1 / 4

    __shared__ __align__(16) unsigned short Hs[48 * SP];
    __shared__ float ssqs[8][48];

    const int R0 = blockIdx.x * 40;
    int deg, seg;
    if (R0 < 100000)      { deg = 1; seg = 0;      }
    else if (R0 < 275000) { deg = 2; seg = 100000; }
    else if (R0 < 425000) { deg = 3; seg = 275000; }
    else                  { deg = 4; seg = 425000; }
    const int B40 = R0 - seg;

    if constexpr (BF16IN) {
        const unsigned short* x = (const unsigned short*)xin;
        switch (deg) {
            case 1: gather_bf16<1, SP>(Hs, x, bondf, an1, bn1, seg, B40); break;
            case 2: gather_bf16<2, SP>(Hs, x, bondf, an2, bn2, seg, B40); break;
            case 3: gather_bf16<3, SP>(Hs, x, bondf, an3, bn3, seg, B40); break;
            default: gather_bf16<4, SP>(Hs, x, bondf, an4, bn4, seg, B40); break;
        }
    } else {
        const float* x = (const float*)xin;
        switch (deg) {
            case 1: gather_f32<1, SP>(Hs, x, bondf, an1, bn1, seg, B40); break;
            case 2: gather_f32<2, SP>(Hs, x, bondf, an2, bn2, seg, B40); break;
            case 3: gather_f32<3, SP>(Hs, x, bondf, an3, bn3, seg, B40); break;
            default: gather_f32<4, SP>(Hs, x, bondf, an4, bn4, seg, B40); break;
        }
    }
    __syncthreads();

    // ---- MFMA GEMM: 3 M-tiles (48 rows) x NT N-tiles over 8 waves, K = KP
    const int lane = threadIdx.x & 63;
    const int wv   = threadIdx.x >> 6;     // 0..7
    const int n16  = lane & 15;
    const int quad = lane >> 4;

    float4v acc[JMAX][3];
    #pragma unroll
    for (int j = 0; j < JMAX; ++j)
        #pragma unroll
        for (int mt = 0; mt < 3; ++mt)
            acc[j][mt] = (float4v){0.f, 0.f, 0.f, 0.f};

    const unsigned short* Wb = Wt + (size_t)(deg - 1) * F_OUT_PAD * KP;

    for (int kk = 0; kk < KP; kk += 32) {
        short8 a[3];
        #pragma unroll
        for (int mt = 0; mt < 3; ++mt)
            a[mt] = *(const short8*)&Hs[(mt * 16 + n16) * SP + kk + quad * 8];
        short8 b[JMAX];
        #pragma unroll
        for (int j = 0; j < JMAX; ++j) {
            const int nt = wv + 8 * j;
            if (nt < NT)
                b[j] = *(const short8*)(Wb + (size_t)(nt * 16 + n16) * KP + kk + quad * 8);
        }
        #pragma unroll
        for (int j = 0; j < JMAX; ++j) {
            const int nt = wv + 8 * j;
            if (nt < NT)
                #pragma unroll
                for (int mt = 0; mt < 3; ++mt)
                    acc[j][mt] = __builtin_amdgcn_mfma_f32_16x16x32_bf16(
                        a[mt], b[j], acc[j][mt], 0, 0, 0);
        }
    }

    // ---- epilogue: bias, row ssq (quad shfl + cross-wave LDS), normalize
    // C/D layout: col = nt*16 + n16, row = mt*16 + quad*4 + r
    float ssq[3][4];
    #pragma unroll
    for (int mt = 0; mt < 3; ++mt)
        #pragma unroll
        for (int r = 0; r < 4; ++r) ssq[mt][r] = 0.f;

    #pragma unroll
    for (int j = 0; j < JMAX; ++j) {
        const int nt = wv + 8 * j;
        if (nt < NT) {
            const float bj = bcomb[(deg - 1) * F_OUT_PAD + nt * 16 + n16];
            #pragma unroll
            for (int mt = 0; mt < 3; ++mt)
                #pragma unroll
                for (int r = 0; r < 4; ++r) {
                    float t = acc[j][mt][r] + bj;
                    acc[j][mt][r] = t;
                    ssq[mt][r] += t * t;
                }
        }
    }
    #pragma unroll
    for (int off = 1; off <= 8; off <<= 1)
        #pragma unroll
        for (int mt = 0; mt < 3; ++mt)
            #pragma unroll
            for (int r = 0; r < 4; ++r)
                ssq[mt][r] += __shfl_xor(ssq[mt][r], off);
    if (n16 == 0)
        #pragma unroll
        for (int mt = 0; mt < 3; ++mt)
            #pragma unroll
            for (int r = 0; r < 4; ++r)
                ssqs[wv][mt * 16 + quad * 4 + r] = ssq[mt][r];
    __syncthreads();

    float rn[3][4];
    #pragma unroll
    for (int mt = 0; mt < 3; ++mt)
        #pragma unroll
        for (int r = 0; r < 4; ++r) {
            const int row = mt * 16 + quad * 4 + r;
            float s = 0.f;
            #pragma unroll
            for (int w = 0; w < 8; ++w) s += ssqs[w][row];
            rn[mt][r] = 1.0f / fmaxf(sqrtf(s), 1e-12f);
        }

    if constexpr (!LAST) {
        #pragma unroll
        for (int j = 0; j < JMAX; ++j) {
            const int nt = wv + 8 * j;
            if (nt < NT) {
                const int col = nt * 16 + n16;
                if (col < F_OUT) {
                    #pragma unroll
                    for (int mt = 0; mt < 3; ++mt)
                        #pragma unroll
                        for (int r = 0; r < 4; ++r) {
                            const int row = mt * 16 + quad * 4 + r;
                            if (row < 40) {
                                const float v = fmaxf(acc[j][mt][r] * rn[mt][r], 0.f);
                                xout[(size_t)(R0 + row) * XS + col] = f2bf(v);
                            }
                        }
                }
            }
        }
    } else {
        // fused molecule segment-sum: rows 0..19 -> mol 2*bid, 20..39 -> 2*bid+1
        #pragma unroll
        for (int j = 0; j < JMAX; ++j) {
            float m0 = 0.f, m1 = 0.f;
            #pragma unroll
            for (int mt = 0; mt < 3; ++mt)
                #pragma unroll
                for (int r = 0; r < 4; ++r) {
                    const int row = mt * 16 + quad * 4 + r;
                    if (row < 40) {
                        const float v = fmaxf(acc[j][mt][r] * rn[mt][r], 0.f);
                        if (row < 20) m0 += v; else m1 += v;
                    }
                }
            m0 += __shfl_xor(m0, 16); m0 += __shfl_xor(m0, 32);
            m1 += __shfl_xor(m1, 16); m1 += __shfl_xor(m1, 32);
            if (quad == 0) {
                const int col = (wv + 8 * j) * 16 + n16;
                molout[(size_t)(2 * blockIdx.x)     * 512 + col] = m0;
                molout[(size_t)(2 * blockIdx.x + 1) * 512 + col] = m1;
            }
        }
    }
}

extern "C" void kernel_launch(void* const* d_in, const int* in_sizes, int n_in,
                              void* d_out, int out_size, void* d_ws, size_t ws_size,
                              hipStream_t stream) {
    const bool sig_order = (in_sizes[3] != 100000);

    const float* atomf = (const float*)d_in[0];   // [500000,62]
    const float* bondf = (const float*)d_in[1];   // [600000,6]
    const int *an1, *bn1, *an2, *bn2, *an3, *bn3, *an4, *bn4;
    const float *Ws0, *bs0, *Wd0, *bd0;
    const float *Ws1, *bs1, *Wd1, *bd1;
    const float *Ws2, *bs2, *Wd2, *bd2;

    if (!sig_order) {
        an1 = (const int*)d_in[2];  bn1 = (const int*)d_in[3];
        an2 = (const int*)d_in[4];  bn2 = (const int*)d_in[5];
        an3 = (const int*)d_in[6];  bn3 = (const int*)d_in[7];
        an4 = (const int*)d_in[8];  bn4 = (const int*)d_in[9];
        Ws0 = (const float*)d_in[11]; bs0 = (const float*)d_in[12];
        Wd0 = (const float*)d_in[13]; bd0 = (const float*)d_in[14];
        Ws1 = (const float*)d_in[15]; bs1 = (const float*)d_in[16];
        Wd1 = (const float*)d_in[17]; bd1 = (const float*)d_in[18];
        Ws2 = (const float*)d_in[19]; bs2 = (const float*)d_in[20];
        Wd2 = (const float*)d_in[21]; bd2 = (const float*)d_in[22];
    } else {
        an1 = (const int*)d_in[2];  an2 = (const int*)d_in[3];
        an3 = (const int*)d_in[4];  an4 = (const int*)d_in[5];
        bn1 = (const int*)d_in[6];  bn2 = (const int*)d_in[7];
        bn3 = (const int*)d_in[8];  bn4 = (const int*)d_in[9];
        Ws0 = (const float*)d_in[11]; bs0 = (const float*)d_in[12];
        Ws1 = (const float*)d_in[13]; bs1 = (const float*)d_in[14];
        Ws2 = (const float*)d_in[15]; bs2 = (const float*)d_in[16];
        Wd0 = (const float*)d_in[17]; bd0 = (const float*)d_in[18];
        Wd1 = (const float*)d_in[19]; bd1 = (const float*)d_in[20];
        Wd2 = (const float*)d_in[21]; bd2 = (const float*)d_in[22];
    }

    // workspace layout (201,273,344 B total — proven footprint)
    char* w = (char*)d_ws;
    unsigned short* x1  = (unsigned short*)w;                        // 100,000,000 B
    unsigned short* x2  = (unsigned short*)(w + 100000000);          // 100,000,000 B
    unsigned short* Wt0 = (unsigned short*)(w + 200000000);          // 4*112*160*2 = 143360
    float*          bc0 = (float*)(w + 200143360);                   // 1792
    unsigned short* Wt1 = (unsigned short*)(w + 200145152);          // 4*112*224*2 = 200704
    float*          bc1 = (float*)(w + 200345856);                   // 1792
    unsigned short* Wt2 = (unsigned short*)(w + 200347648);          // 4*512*224*2 = 917504
    float*          bc2 = (float*)(w + 201265152);                   // 8192

    prep_weights<<<(4 * 112 * 160 + 255) / 256, 256, 0, stream>>>(
        Ws0, bs0, Wd0, bd0, 62, 100, 112, 160, 64, Wt0, bc0);
    prep_weights<<<(4 * 112 * 224 + 255) / 256, 256, 0, stream>>>(
        Ws1, bs1, Wd1, bd1, 100, 100, 112, 224, 104, Wt1, bc1);
    prep_weights<<<(4 * 512 * 224 + 255) / 256, 256, 0, stream>>>(
        Ws2, bs2, Wd2, bd2, 100, 512, 512, 224, 104, Wt2, bc2);

    dim3 grid(12500), block(512);
    layer_mfma<62, 100, 112, 64, false, false><<<grid, block, 0, stream>>>(
        atomf, bondf, an1, bn1, an2, bn2, an3, bn3, an4, bn4,
        Wt0, bc0, x1, nullptr);
    layer_mfma<100, 100, 112, 104, false, true><<<grid, block, 0, stream>>>(
        x1, bondf, an1, bn1, an2, bn2, an3, bn3, an4, bn4,
        Wt1, bc1, x2, nullptr);
    layer_mfma<100, 512, 512, 104, true, true><<<grid, block, 0, stream>>>(
        x2, bondf, an1, bn1, an2, bn2, an3, bn3, an4, bn4,
        Wt2, bc2, nullptr, (float*)d_out);
}